// Round 5
// baseline (159.900 us; speedup 1.0000x reference)
//
#include <hip/hip_runtime.h>

// Problem constants (N=1, C=64, H=W=80)
#define LDIM 6400
#define CDIM 64
#define WDIM 80
#define NEGV -1e9f

// Orderable (ascending) encoding of fp32.
__device__ __forceinline__ unsigned encf(float f) {
    unsigned b = __float_as_uint(f);
    return (b & 0x80000000u) ? ~b : (b | 0x80000000u);
}
__device__ __forceinline__ float decf(unsigned e) {
    unsigned b = (e & 0x80000000u) ? (e ^ 0x80000000u) : ~e;
    return __uint_as_float(b);
}

// init: zero rowp/colenc/counter + write data-independent mkpts0 (25 blocks)
__global__ void init_kernel(unsigned long long* __restrict__ rowp,
                            unsigned* __restrict__ colenc,
                            unsigned* __restrict__ cnt,
                            float* __restrict__ out) {
    int i = blockIdx.x * 256 + threadIdx.x;
    if (i < LDIM) {
        rowp[i] = 0ull;
        colenc[i] = 0u;
        out[2 * i]     = (float)((i % WDIM) * 8);
        out[2 * i + 1] = (float)((i / WDIM) * 8);
    }
    if (i == 0) *cnt = 0u;
}

// main: blocks [0,2500) = conf tiles (128x128, 8x8 microtile, two 32-ch slabs,
// 32 KB LDS); blocks [2500,4100) = bilinear x8 upsample. The LAST conf block
// to finish (atomic counter) performs the mutual-NN finalize, reading
// rowp/colenc via non-mutating atomics (coherent L2 view across XCDs).
// __launch_bounds__(256,4): VGPR cap 128 (kernel wants ~64-90; (256,5)
// squeezed to 48 and spilled the accumulator -> 544 MB scratch, R3 regression).
__global__ __launch_bounds__(256, 4) void main_kernel(
        const float* __restrict__ A, const float* __restrict__ B,
        const float* __restrict__ sav, const float* __restrict__ sai,
        unsigned long long* __restrict__ rowp, unsigned* __restrict__ colenc,
        unsigned* __restrict__ cnt, float* __restrict__ out) {
    __shared__ float As[32][128];   // 16 KB
    __shared__ float Bs[32][128];   // 16 KB
    __shared__ unsigned last_old;
    const int tid = threadIdx.x;
    const int b = blockIdx.x;

    if (b >= 2500) {
        // ---- upsample path ----
        int i = (b - 2500) * 256 + tid;   // < 640*640
        int oy = i / 640, ox = i % 640;
        const float step = 79.0f / 639.0f;
        float fy = (float)oy * step;
        float fx = (float)ox * step;
        int y0 = (int)floorf(fy); if (y0 > 79) y0 = 79; if (y0 < 0) y0 = 0;
        int x0 = (int)floorf(fx); if (x0 > 79) x0 = 79; if (x0 < 0) x0 = 0;
        int y1 = (y0 + 1 < 80) ? y0 + 1 : 79;
        int x1 = (x0 + 1 < 80) ? x0 + 1 : 79;
        float wy = fy - (float)y0;
        float wx = fx - (float)x0;
        float v00 = sai[y0 * 80 + x0], v01 = sai[y0 * 80 + x1];
        float v10 = sai[y1 * 80 + x0], v11 = sai[y1 * 80 + x1];
        float r0 = v00 * (1.0f - wy) + v10 * wy;
        float r1 = v01 * (1.0f - wy) + v11 * wy;
        out[38400 + i] = r0 * (1.0f - wx) + r1 * wx;
        return;
    }

    // ---- conf tile path ----
    const int lb = (b / 50) * 128;   // row (vi) base
    const int sb = (b % 50) * 128;   // col (ir) base
    const int tx = tid & 15, ty = tid >> 4;

    float acc[8][8];
    #pragma unroll
    for (int i = 0; i < 8; ++i)
        #pragma unroll
        for (int j = 0; j < 8; ++j) acc[i][j] = 0.0f;

    float4* As4 = (float4*)As;
    float4* Bs4 = (float4*)Bs;
    const float4* pA = (const float4*)As;
    const float4* pB = (const float4*)Bs;

    for (int kb = 0; kb < 2; ++kb) {
        #pragma unroll
        for (int i = tid, it = 0; it < 4; i += 256, ++it) {
            int c = i >> 5, q = i & 31;
            As4[i] = ((const float4*)(A + (kb * 32 + c) * LDIM + lb))[q];
            Bs4[i] = ((const float4*)(B + (kb * 32 + c) * LDIM + sb))[q];
        }
        __syncthreads();

        #pragma unroll 4
        for (int c = 0; c < 32; ++c) {
            float4 a0 = pA[(c << 5) + ty];
            float4 a1 = pA[(c << 5) + ty + 16];
            float4 b0 = pB[(c << 5) + tx];
            float4 b1 = pB[(c << 5) + tx + 16];
            float av[8] = {a0.x, a0.y, a0.z, a0.w, a1.x, a1.y, a1.z, a1.w};
            float bv[8] = {b0.x, b0.y, b0.z, b0.w, b1.x, b1.y, b1.z, b1.w};
            #pragma unroll
            for (int i = 0; i < 8; ++i)
                #pragma unroll
                for (int j = 0; j < 8; ++j)
                    acc[i][j] = fmaf(av[i], bv[j], acc[i][j]);
        }
        __syncthreads();
    }

    int rg[8], cg[8];
    #pragma unroll
    for (int i = 0; i < 8; ++i) {
        rg[i] = lb + ty * 4 + ((i < 4) ? i : (64 + i - 4));
        cg[i] = sb + tx * 4 + ((i < 4) ? i : (64 + i - 4));
    }
    bool rok[8], cok[8];
    #pragma unroll
    for (int i = 0; i < 8; ++i) rok[i] = sav[rg[i]] > 0.0f;
    #pragma unroll
    for (int j = 0; j < 8; ++j) cok[j] = sai[cg[j]] > 0.0f;

    float conf[8][8];
    #pragma unroll
    for (int i = 0; i < 8; ++i)
        #pragma unroll
        for (int j = 0; j < 8; ++j)
            conf[i][j] = (rok[i] && cok[j]) ? acc[i][j] * 0.15625f : NEGV;

    // ---- row reduction in float domain; encode+pack once per row ----
    #pragma unroll
    for (int i = 0; i < 8; ++i) {
        float v = conf[i][0];
        int ci = cg[0];
        #pragma unroll
        for (int j = 1; j < 8; ++j) {      // strict > keeps earliest index
            bool up = conf[i][j] > v;
            v = up ? conf[i][j] : v;
            ci = up ? cg[j] : ci;
        }
        #pragma unroll
        for (int d = 1; d < 16; d <<= 1) { // 16-lane butterfly (wave-aligned)
            float ov = __shfl_xor(v, d, 64);
            int oi = __shfl_xor(ci, d, 64);
            bool take = (ov > v) || ((ov == v) && (oi < ci));
            v = take ? ov : v;
            ci = take ? oi : ci;
        }
        if (tx == 0)
            atomicMax(&rowp[rg[i]],
                      ((unsigned long long)encf(v) << 32) |
                      (unsigned)(~(unsigned)ci));
    }

    // ---- col reduction via LDS (reuse As/Bs; stride 17 -> 2-way, free) ----
    __syncthreads();
    float* cred = &As[0][0];
    #pragma unroll
    for (int j = 0; j < 8; ++j) {
        float m = conf[0][j];
        #pragma unroll
        for (int i = 1; i < 8; ++i) m = fmaxf(m, conf[i][j]);
        int cl = tx * 4 + ((j < 4) ? j : (64 + j - 4));
        cred[cl * 17 + ty] = m;
    }
    __syncthreads();
    if (tid < 128) {
        float m = cred[tid * 17];
        #pragma unroll
        for (int t = 1; t < 16; ++t) m = fmaxf(m, cred[tid * 17 + t]);
        atomicMax(&colenc[sb + tid], encf(m));
    }

    // ---- last-block finalize ----
    __syncthreads();   // barrier drains vmcnt(0): this block's atomics retired
    if (tid == 0) {
        __threadfence();
        last_old = atomicAdd(cnt, 1u);
    }
    __syncthreads();
    if (last_old == 2499u) {
        __threadfence();
        for (int l = tid; l < LDIM; l += 256) {
            unsigned long long p = atomicMax(&rowp[l], 0ull);   // coherent read
            unsigned enc = (unsigned)(p >> 32);
            unsigned s = ~((unsigned)p);       // row argmax col (first on ties)
            float val = decf(enc);
            unsigned ce = atomicMax(&colenc[s], 0u);            // coherent read
            bool mk = (enc == ce) && (val > 0.0f);
            int aj = mk ? (int)s : 0;          // argmax(mask)==0 when row empty
            out[12800 + 2 * l]     = (float)((aj % WDIM) * 8);
            out[12800 + 2 * l + 1] = (float)((aj / WDIM) * 8);
            out[25600 + l] = mk ? 1.0f : 0.0f;
            out[32000 + l] = mk ? val : 0.0f;
        }
    }
}

extern "C" void kernel_launch(void* const* d_in, const int* in_sizes, int n_in,
                              void* d_out, int out_size, void* d_ws, size_t ws_size,
                              hipStream_t stream) {
    const float* frv = (const float*)d_in[0];  // feat_reg_vi [64,6400]
    const float* fri = (const float*)d_in[1];  // feat_reg_ir [64,6400]
    const float* sav = (const float*)d_in[2];  // feat_sa_vi  [6400]
    const float* sai = (const float*)d_in[3];  // feat_sa_ir  [6400]
    float* out = (float*)d_out;

    unsigned long long* rowp = (unsigned long long*)d_ws;
    unsigned* colenc = (unsigned*)((char*)d_ws + LDIM * sizeof(unsigned long long));
    unsigned* cnt = (unsigned*)((char*)d_ws + LDIM * 12);

    init_kernel<<<25, 256, 0, stream>>>(rowp, colenc, cnt, out);
    main_kernel<<<4100, 256, 0, stream>>>(frv, fri, sav, sai, rowp, colenc, cnt, out);
}

// Round 6
// 133.306 us; speedup vs baseline: 1.1995x; 1.1995x over previous
//
#include <hip/hip_runtime.h>

// Problem constants (N=1, C=64, H=W=80)
#define LDIM 6400
#define CDIM 64
#define WDIM 80
#define NEGV -1e9f

// Orderable (ascending) encoding of fp32.
__device__ __forceinline__ unsigned encf(float f) {
    unsigned b = __float_as_uint(f);
    return (b & 0x80000000u) ? ~b : (b | 0x80000000u);
}
__device__ __forceinline__ float decf(unsigned e) {
    unsigned b = (e & 0x80000000u) ? (e ^ 0x80000000u) : ~e;
    return __uint_as_float(b);
}

// init: zero rowp/colenc + write data-independent mkpts0 (25 blocks, ~2 us)
__global__ void init_kernel(unsigned long long* __restrict__ rowp,
                            unsigned* __restrict__ colenc,
                            float* __restrict__ out) {
    int i = blockIdx.x * 256 + threadIdx.x;
    if (i < LDIM) {
        rowp[i] = 0ull;
        colenc[i] = 0u;
        out[2 * i]     = (float)((i % WDIM) * 8);
        out[2 * i + 1] = (float)((i / WDIM) * 8);
    }
}

// main: blocks [0,2500) = conf tiles (128x128, 8x8 microtile, two 32-ch
// slabs, LDS exactly 32768 B -> 5 blocks/CU ceiling); blocks [2500,4100) =
// bilinear x8 upsample (dispatched after conf -> backfills the tail).
// NO extra __shared__ (R5 post-mortem: +4B shared -> LDS 33280 -> 4 blocks/CU,
// VALUBusy 68->47%). NO per-block threadfence/counter (R5 tail serialization).
// __launch_bounds__(256,4): VGPR cap 128 (R3: (256,5) squeezed to 48 VGPRs,
// spilled the 64-float accumulator -> 544 MB scratch writes, 2.8x regression).
__global__ __launch_bounds__(256, 4) void main_kernel(
        const float* __restrict__ A, const float* __restrict__ B,
        const float* __restrict__ sav, const float* __restrict__ sai,
        unsigned long long* __restrict__ rowp, unsigned* __restrict__ colenc,
        float* __restrict__ out) {
    __shared__ float As[32][128];   // 16 KB
    __shared__ float Bs[32][128];   // 16 KB
    const int tid = threadIdx.x;
    const int b = blockIdx.x;

    if (b >= 2500) {
        // ---- upsample path ----
        int i = (b - 2500) * 256 + tid;   // < 640*640
        int oy = i / 640, ox = i % 640;
        const float step = 79.0f / 639.0f;
        float fy = (float)oy * step;
        float fx = (float)ox * step;
        int y0 = (int)floorf(fy); if (y0 > 79) y0 = 79; if (y0 < 0) y0 = 0;
        int x0 = (int)floorf(fx); if (x0 > 79) x0 = 79; if (x0 < 0) x0 = 0;
        int y1 = (y0 + 1 < 80) ? y0 + 1 : 79;
        int x1 = (x0 + 1 < 80) ? x0 + 1 : 79;
        float wy = fy - (float)y0;
        float wx = fx - (float)x0;
        float v00 = sai[y0 * 80 + x0], v01 = sai[y0 * 80 + x1];
        float v10 = sai[y1 * 80 + x0], v11 = sai[y1 * 80 + x1];
        float r0 = v00 * (1.0f - wy) + v10 * wy;
        float r1 = v01 * (1.0f - wy) + v11 * wy;
        out[38400 + i] = r0 * (1.0f - wx) + r1 * wx;
        return;
    }

    // ---- conf tile path ----
    const int lb = (b / 50) * 128;   // row (vi) base
    const int sb = (b % 50) * 128;   // col (ir) base
    const int tx = tid & 15, ty = tid >> 4;

    float acc[8][8];
    #pragma unroll
    for (int i = 0; i < 8; ++i)
        #pragma unroll
        for (int j = 0; j < 8; ++j) acc[i][j] = 0.0f;

    float4* As4 = (float4*)As;
    float4* Bs4 = (float4*)Bs;
    const float4* pA = (const float4*)As;
    const float4* pB = (const float4*)Bs;

    for (int kb = 0; kb < 2; ++kb) {
        // stage 32-channel slab as float4 (rows 512 B apart, 16B-aligned)
        #pragma unroll
        for (int i = tid, it = 0; it < 4; i += 256, ++it) {
            int c = i >> 5, q = i & 31;
            As4[i] = ((const float4*)(A + (kb * 32 + c) * LDIM + lb))[q];
            Bs4[i] = ((const float4*)(B + (kb * 32 + c) * LDIM + sb))[q];
        }
        __syncthreads();

        #pragma unroll 4
        for (int c = 0; c < 32; ++c) {
            float4 a0 = pA[(c << 5) + ty];
            float4 a1 = pA[(c << 5) + ty + 16];
            float4 b0 = pB[(c << 5) + tx];
            float4 b1 = pB[(c << 5) + tx + 16];
            float av[8] = {a0.x, a0.y, a0.z, a0.w, a1.x, a1.y, a1.z, a1.w};
            float bv[8] = {b0.x, b0.y, b0.z, b0.w, b1.x, b1.y, b1.z, b1.w};
            #pragma unroll
            for (int i = 0; i < 8; ++i)
                #pragma unroll
                for (int j = 0; j < 8; ++j)
                    acc[i][j] = fmaf(av[i], bv[j], acc[i][j]);
        }
        __syncthreads();   // drain reads before next slab overwrite / epilogue
    }

    int rg[8], cg[8];
    #pragma unroll
    for (int i = 0; i < 8; ++i) {
        rg[i] = lb + ty * 4 + ((i < 4) ? i : (64 + i - 4));
        cg[i] = sb + tx * 4 + ((i < 4) ? i : (64 + i - 4));
    }
    bool rok[8], cok[8];
    #pragma unroll
    for (int i = 0; i < 8; ++i) rok[i] = sav[rg[i]] > 0.0f;   // L2-hit broadcast
    #pragma unroll
    for (int j = 0; j < 8; ++j) cok[j] = sai[cg[j]] > 0.0f;

    float conf[8][8];
    #pragma unroll
    for (int i = 0; i < 8; ++i)
        #pragma unroll
        for (int j = 0; j < 8; ++j)
            conf[i][j] = (rok[i] && cok[j]) ? acc[i][j] * 0.15625f : NEGV;

    // ---- row reduction in float domain; encode+pack once per row ----
    #pragma unroll
    for (int i = 0; i < 8; ++i) {
        float v = conf[i][0];
        int ci = cg[0];
        #pragma unroll
        for (int j = 1; j < 8; ++j) {      // strict > keeps earliest index
            bool up = conf[i][j] > v;
            v = up ? conf[i][j] : v;
            ci = up ? cg[j] : ci;
        }
        #pragma unroll
        for (int d = 1; d < 16; d <<= 1) { // 16-lane butterfly (wave-aligned)
            float ov = __shfl_xor(v, d, 64);
            int oi = __shfl_xor(ci, d, 64);
            bool take = (ov > v) || ((ov == v) && (oi < ci));
            v = take ? ov : v;
            ci = take ? oi : ci;
        }
        if (tx == 0)
            atomicMax(&rowp[rg[i]],
                      ((unsigned long long)encf(v) << 32) |
                      (unsigned)(~(unsigned)ci));
    }

    // ---- col reduction via LDS (reuse As/Bs; stride 17 -> 2-way, free) ----
    __syncthreads();
    float* cred = &As[0][0];   // [col 0..127][ty 0..15], stride 17 (fits 4096)
    #pragma unroll
    for (int j = 0; j < 8; ++j) {
        float m = conf[0][j];
        #pragma unroll
        for (int i = 1; i < 8; ++i) m = fmaxf(m, conf[i][j]);
        int cl = tx * 4 + ((j < 4) ? j : (64 + j - 4));
        cred[cl * 17 + ty] = m;
    }
    __syncthreads();
    if (tid < 128) {
        float m = cred[tid * 17];
        #pragma unroll
        for (int t = 1; t < 16; ++t) m = fmaxf(m, cred[tid * 17 + t]);
        atomicMax(&colenc[sb + tid], encf(m));
    }
}

// finalize: mutual-NN check + write mkpts1/mask_v/score (25 blocks, ~2 us)
__global__ void finalize_kernel(const unsigned long long* __restrict__ rowp,
                                const unsigned* __restrict__ colenc,
                                float* __restrict__ out) {
    int l = blockIdx.x * 256 + threadIdx.x;
    if (l >= LDIM) return;
    unsigned long long p = rowp[l];
    unsigned enc = (unsigned)(p >> 32);
    unsigned s = ~((unsigned)p);          // row argmax column (first on ties)
    float val = decf(enc);
    bool mk = (enc == colenc[s]) && (val > 0.0f);
    int aj = mk ? (int)s : 0;             // argmax(mask) == 0 when mask row empty
    out[12800 + 2 * l]     = (float)((aj % WDIM) * 8);
    out[12800 + 2 * l + 1] = (float)((aj / WDIM) * 8);
    out[25600 + l] = mk ? 1.0f : 0.0f;
    out[32000 + l] = mk ? val : 0.0f;
}

extern "C" void kernel_launch(void* const* d_in, const int* in_sizes, int n_in,
                              void* d_out, int out_size, void* d_ws, size_t ws_size,
                              hipStream_t stream) {
    const float* frv = (const float*)d_in[0];  // feat_reg_vi [64,6400]
    const float* fri = (const float*)d_in[1];  // feat_reg_ir [64,6400]
    const float* sav = (const float*)d_in[2];  // feat_sa_vi  [6400]
    const float* sai = (const float*)d_in[3];  // feat_sa_ir  [6400]
    float* out = (float*)d_out;

    unsigned long long* rowp = (unsigned long long*)d_ws;
    unsigned* colenc = (unsigned*)((char*)d_ws + LDIM * sizeof(unsigned long long));

    init_kernel<<<25, 256, 0, stream>>>(rowp, colenc, out);
    main_kernel<<<4100, 256, 0, stream>>>(frv, fri, sav, sai, rowp, colenc, out);
    finalize_kernel<<<25, 256, 0, stream>>>(rowp, colenc, out);
}